// Round 1
// baseline (459.705 us; speedup 1.0000x reference)
//
#include <hip/hip_runtime.h>

typedef unsigned short u16;
typedef u16 u16x8 __attribute__((ext_vector_type(8)));
typedef u16 u16x4 __attribute__((ext_vector_type(4)));
typedef __bf16 bf16x8_t __attribute__((ext_vector_type(8)));
typedef float f32x4 __attribute__((ext_vector_type(4)));

#define GLOBAL_AS __attribute__((address_space(1)))
#define LDS_AS __attribute__((address_space(3)))

__device__ __forceinline__ float bf2f(u16 v) {
    return __uint_as_float(((unsigned int)v) << 16);
}
__device__ __forceinline__ u16 f2bf(float f) {
    unsigned int u = __float_as_uint(f);
    u += 0x7fff + ((u >> 16) & 1);   // RTNE (no NaNs in this pipeline)
    return (u16)(u >> 16);
}

__device__ __forceinline__ f32x4 mfma_bf16(u16x8 a, u16x8 b, f32x4 c) {
    return __builtin_amdgcn_mfma_f32_16x16x32_bf16(
        __builtin_bit_cast(bf16x8_t, a), __builtin_bit_cast(bf16x8_t, b), c, 0, 0, 0);
}

// ---------------- fp32 -> bf16 convert ----------------
__global__ __launch_bounds__(256) void cvt_kernel(const float* __restrict__ in,
                                                  u16* __restrict__ out, int n4) {
    int i = blockIdx.x * 256 + threadIdx.x;
    if (i >= n4) return;
    float4 f = ((const float4*)in)[i];
    u16x4 o = { f2bf(f.x), f2bf(f.y), f2bf(f.z), f2bf(f.w) };
    ((u16x4*)out)[i] = o;
}

// ---------------- keep-mask width sniffing + expand ----------------
// mask[0][0] and mask[0][1] are guaranteed true (lengths >= L/2 = 1024).
__global__ __launch_bounds__(256) void mask_prep(const unsigned char* __restrict__ raw,
                                                 unsigned char* __restrict__ keep, int n) {
    int i = blockIdx.x * 256 + threadIdx.x;
    if (i >= n) return;
    unsigned char b0 = raw[0];
    unsigned char v;
    if (b0 == 0) {                       // fp32 pattern (1.0f -> bytes 0,0,0x80,0x3f)
        v = (((const float*)raw)[i] != 0.0f) ? 1 : 0;
    } else if (b0 == 0x80) {             // bf16 pattern (1.0 -> 0x3F80)
        v = (((const u16*)raw)[i] != 0) ? 1 : 0;
    } else {                             // integer of width 1/2/4/8
        int stride = raw[1] ? 1 : (raw[2] ? 2 : (raw[4] ? 4 : 8));
        v = (raw[(size_t)i * stride] != 0) ? 1 : 0;
    }
    keep[i] = v;
}

// ---------------- 128x128 bf16 GEMM, C = A(MxK) * B(NxK)^T ----------------
// MODE 0: scatter to q/k/v (B,H,L,hd) bf16.  MODE 1: fp32 out[M][N].
template <int MODE>
__global__ __launch_bounds__(256, 2) void gemm_bt(
    const u16* __restrict__ A, const u16* __restrict__ B,
    int M, int N, int K,
    u16* __restrict__ qp, u16* __restrict__ kp, u16* __restrict__ vp,
    float* __restrict__ outf) {
    __shared__ u16 lA[128 * 64];
    __shared__ u16 lB[128 * 64];
    const int tid  = threadIdx.x;
    const int lane = tid & 63;
    const int wid  = tid >> 6;
    const int wr   = wid >> 1, wc = wid & 1;
    const int brow = blockIdx.y * 128;
    const int bcol = blockIdx.x * 128;

    f32x4 acc[4][4];
#pragma unroll
    for (int m = 0; m < 4; ++m)
#pragma unroll
        for (int n = 0; n < 4; ++n)
            acc[m][n] = (f32x4){0.f, 0.f, 0.f, 0.f};

    const int r0 = tid >> 3;          // staging row within 32-row slab
    const int c0 = (tid & 7) * 16;    // staging byte-col within 128B row

    const int nkt = K >> 6;
    for (int kt = 0; kt < nkt; ++kt) {
#pragma unroll
        for (int i = 0; i < 4; ++i) {
            const int row = i * 32 + r0;
            const u16* ga = A + (size_t)(brow + row) * K + kt * 64 + (c0 >> 1);
            const u16* gb = B + (size_t)(bcol + row) * K + kt * 64 + (c0 >> 1);
            __builtin_amdgcn_global_load_lds((const GLOBAL_AS void*)ga,
                (LDS_AS void*)((char*)lA + i * 4096 + wid * 1024), 16, 0, 0);
            __builtin_amdgcn_global_load_lds((const GLOBAL_AS void*)gb,
                (LDS_AS void*)((char*)lB + i * 4096 + wid * 1024), 16, 0, 0);
        }
        __syncthreads();
#pragma unroll
        for (int ks = 0; ks < 2; ++ks) {
            u16x8 af[4], bfv[4];
#pragma unroll
            for (int m = 0; m < 4; ++m)
                af[m] = *(const u16x8*)&lA[(wr * 64 + m * 16 + (lane & 15)) * 64 + ks * 32 + (lane >> 4) * 8];
#pragma unroll
            for (int n = 0; n < 4; ++n)
                bfv[n] = *(const u16x8*)&lB[(wc * 64 + n * 16 + (lane & 15)) * 64 + ks * 32 + (lane >> 4) * 8];
#pragma unroll
            for (int m = 0; m < 4; ++m)
#pragma unroll
                for (int n = 0; n < 4; ++n)
                    acc[m][n] = mfma_bf16(af[m], bfv[n], acc[m][n]);
        }
        __syncthreads();
    }

#pragma unroll
    for (int m = 0; m < 4; ++m) {
#pragma unroll
        for (int n = 0; n < 4; ++n) {
#pragma unroll
            for (int j = 0; j < 4; ++j) {
                const int row = brow + wr * 64 + m * 16 + (lane >> 4) * 4 + j;
                const int col = bcol + wc * 64 + n * 16 + (lane & 15);
                const float val = acc[m][n][j];
                if (MODE == 0) {
                    const int part = col >> 11;
                    const int e = col & 2047;
                    const int hh = e >> 7, dd = e & 127;
                    const int bb = row >> 11, ll = row & 2047;
                    u16* dst = (part == 0) ? qp : (part == 1) ? kp : vp;
                    dst[((size_t)(bb * 16 + hh) * 2048 + ll) * 128 + dd] = f2bf(val);
                } else {
                    outf[(size_t)row * N + col] = val;
                }
            }
        }
    }
}

// ---------------- RoPE in-place on q,k (contiguous, (2*B*H*L) rows of 128) ----------------
__global__ __launch_bounds__(256) void rope_kernel(u16* __restrict__ qk,
                                                   const float* __restrict__ cosp,
                                                   const float* __restrict__ sinp) {
    const int gid  = blockIdx.x * 4 + (threadIdx.x >> 6);   // row index
    const int lane = threadIdx.x & 63;
    const int l    = gid & 2047;
    u16* row = qk + (size_t)gid * 128;
    const int d1 = lane, d2 = lane + 64;
    const float v1 = bf2f(row[d1]);
    const float v2 = bf2f(row[d2]);
    const float c1 = cosp[l * 128 + d1], s1 = sinp[l * 128 + d1];
    const float c2 = cosp[l * 128 + d2], s2 = sinp[l * 128 + d2];
    row[d1] = f2bf(v1 * c1 - v2 * s1);   // rot_half: -t[d+64] for d<64
    row[d2] = f2bf(v2 * c2 + v1 * s2);   //           +t[d-64] for d>=64
}

// ---------------- flash attention: causal + key-padding mask ----------------
// grid (16 q-blocks, 32 b*h), 256 threads. Q/K/V: (B,H,L,hd) bf16. O: (B,L,D) bf16, row-masked.
__global__ __launch_bounds__(256, 1) void attn_kernel(
    const u16* __restrict__ Q, const u16* __restrict__ K, const u16* __restrict__ V,
    const unsigned char* __restrict__ keep, u16* __restrict__ O) {
    __shared__ u16 lK[64 * 136];    // padded: row stride 136 elems
    __shared__ u16 lVT[128 * 72];   // V transposed: [d][key], stride 72
    __shared__ u16 lP[4 * 32 * 72]; // per-wave P: [32 q][keys], stride 72

    const int tid = threadIdx.x, lane = tid & 63, wid = tid >> 6;
    const int qi = blockIdx.x;
    const int bh = blockIdx.y;
    const int b  = bh >> 4;
    const int h  = bh & 15;
    const u16* qb = Q + (size_t)bh * 2048 * 128;
    const u16* kb = K + (size_t)bh * 2048 * 128;
    const u16* vb = V + (size_t)bh * 2048 * 128;
    const unsigned char* keepb = keep + b * 2048;
    const int q0 = qi * 128 + wid * 32;

    // Q fragments in registers (already RoPE'd)
    u16x8 aq[2][4];
#pragma unroll
    for (int m = 0; m < 2; ++m)
#pragma unroll
        for (int kc = 0; kc < 4; ++kc)
            aq[m][kc] = *(const u16x8*)(qb + (size_t)(q0 + m * 16 + (lane & 15)) * 128 + kc * 32 + (lane >> 4) * 8);

    float ms[2][4], ls[2][4];
    f32x4 ao[2][8];
#pragma unroll
    for (int m = 0; m < 2; ++m)
#pragma unroll
        for (int j = 0; j < 4; ++j) { ms[m][j] = -1e30f; ls[m][j] = 0.f; }
#pragma unroll
    for (int m = 0; m < 2; ++m)
#pragma unroll
        for (int n = 0; n < 8; ++n)
            ao[m][n] = (f32x4){0.f, 0.f, 0.f, 0.f};

    u16* lPw = lP + wid * (32 * 72);
    const int srow = tid & 63, sdc = tid >> 6;
    const float scale = 0.08838834764831845f;  // 1/sqrt(128)

    const int ntiles = (qi + 1) * 2;
    for (int t = 0; t < ntiles; ++t) {
        const int kv0 = t * 64;
        // ---- stage K rows + V transposed ----
        {
            const u16* ksrc = kb + (size_t)(kv0 + srow) * 128 + sdc * 32;
            const u16* vsrc = vb + (size_t)(kv0 + srow) * 128 + sdc * 32;
#pragma unroll
            for (int i = 0; i < 4; ++i) {
                u16x8 tk = *(const u16x8*)(ksrc + i * 8);
                *(u16x8*)&lK[srow * 136 + sdc * 32 + i * 8] = tk;
                u16x8 tv = *(const u16x8*)(vsrc + i * 8);
#pragma unroll
                for (int e = 0; e < 8; ++e)
                    lVT[(sdc * 32 + i * 8 + e) * 72 + srow] = tv[e];
            }
        }
        __syncthreads();

        // ---- S = Q K^T ----
        f32x4 s[2][4];
#pragma unroll
        for (int m = 0; m < 2; ++m)
#pragma unroll
            for (int n = 0; n < 4; ++n)
                s[m][n] = (f32x4){0.f, 0.f, 0.f, 0.f};
#pragma unroll
        for (int kc = 0; kc < 4; ++kc) {
            u16x8 bk[4];
#pragma unroll
            for (int n = 0; n < 4; ++n)
                bk[n] = *(const u16x8*)&lK[(n * 16 + (lane & 15)) * 136 + kc * 32 + (lane >> 4) * 8];
#pragma unroll
            for (int m = 0; m < 2; ++m)
#pragma unroll
                for (int n = 0; n < 4; ++n)
                    s[m][n] = mfma_bf16(aq[m][kc], bk[n], s[m][n]);
        }

        // ---- masked online softmax (fp32) ----
        bool kok[4];
#pragma unroll
        for (int n = 0; n < 4; ++n)
            kok[n] = keepb[kv0 + n * 16 + (lane & 15)] != 0;

#pragma unroll
        for (int m = 0; m < 2; ++m) {
#pragma unroll
            for (int j = 0; j < 4; ++j) {
                const int qq = q0 + m * 16 + (lane >> 4) * 4 + j;
                float sv[4];
                float rm = -1e30f;
#pragma unroll
                for (int n = 0; n < 4; ++n) {
                    const int kk = kv0 + n * 16 + (lane & 15);
                    sv[n] = (kok[n] && kk <= qq) ? s[m][n][j] * scale : -1e30f;
                    rm = fmaxf(rm, sv[n]);
                }
                rm = fmaxf(rm, __shfl_xor(rm, 1));
                rm = fmaxf(rm, __shfl_xor(rm, 2));
                rm = fmaxf(rm, __shfl_xor(rm, 4));
                rm = fmaxf(rm, __shfl_xor(rm, 8));
                const float mn = fmaxf(ms[m][j], rm);
                const float alpha = __expf(ms[m][j] - mn);
                ms[m][j] = mn;
                float rs = 0.f;
#pragma unroll
                for (int n = 0; n < 4; ++n) {
                    const float p = __expf(sv[n] - mn);  // masked -> exp(-1e30)=0
                    rs += p;
                    lPw[(m * 16 + (lane >> 4) * 4 + j) * 72 + n * 16 + (lane & 15)] = f2bf(p);
                }
                rs += __shfl_xor(rs, 1);
                rs += __shfl_xor(rs, 2);
                rs += __shfl_xor(rs, 4);
                rs += __shfl_xor(rs, 8);
                ls[m][j] = ls[m][j] * alpha + rs;
#pragma unroll
                for (int n = 0; n < 8; ++n)
                    ao[m][n][j] *= alpha;
            }
        }

        // ---- O += P V ----
#pragma unroll
        for (int kc = 0; kc < 2; ++kc) {
            u16x8 ap[2];
#pragma unroll
            for (int m = 0; m < 2; ++m)
                ap[m] = *(const u16x8*)&lPw[(m * 16 + (lane & 15)) * 72 + kc * 32 + (lane >> 4) * 8];
#pragma unroll
            for (int n = 0; n < 8; ++n) {
                u16x8 bv = *(const u16x8*)&lVT[(n * 16 + (lane & 15)) * 72 + kc * 32 + (lane >> 4) * 8];
#pragma unroll
                for (int m = 0; m < 2; ++m)
                    ao[m][n] = mfma_bf16(ap[m], bv, ao[m][n]);
            }
        }
        __syncthreads();
    }

    // ---- epilogue: normalize, row-mask, write (B,L,D) ----
#pragma unroll
    for (int m = 0; m < 2; ++m) {
#pragma unroll
        for (int j = 0; j < 4; ++j) {
            const int qq = q0 + m * 16 + (lane >> 4) * 4 + j;
            const bool kept = keepb[qq] != 0;
            const float inv = kept ? (1.f / ls[m][j]) : 0.f;
#pragma unroll
            for (int n = 0; n < 8; ++n) {
                const int d = n * 16 + (lane & 15);
                O[((size_t)b * 2048 + qq) * 2048 + h * 128 + d] = f2bf(ao[m][n][j] * inv);
            }
        }
    }
}

// ---------------- launch ----------------
extern "C" void kernel_launch(void* const* d_in, const int* in_sizes, int n_in,
                              void* d_out, int out_size, void* d_ws, size_t ws_size,
                              hipStream_t stream) {
    const float* x      = (const float*)d_in[0];
    const unsigned char* maskraw = (const unsigned char*)d_in[1];
    const float* cosp   = (const float*)d_in[2];
    const float* sinp   = (const float*)d_in[3];
    const float* w_qkv  = (const float*)d_in[4];
    const float* w_out  = (const float*)d_in[5];
    float* out = (float*)d_out;

    char* ws = (char*)d_ws;
    size_t off = 0;
    auto alloc = [&](size_t bytes) {
        char* p = ws + off;
        off += (bytes + 255) & ~(size_t)255;
        return p;
    };
    u16* xb    = (u16*)alloc((size_t)4096 * 2048 * 2);
    u16* wqkvb = (u16*)alloc((size_t)6144 * 2048 * 2);
    u16* woutb = (u16*)alloc((size_t)2048 * 2048 * 2);
    u16* qB    = (u16*)alloc((size_t)65536 * 128 * 2);  // (B,H,L,hd)
    u16* kB    = (u16*)alloc((size_t)65536 * 128 * 2);  // contiguous after qB (rope relies on it)
    u16* vB    = (u16*)alloc((size_t)65536 * 128 * 2);
    u16* attno = (u16*)alloc((size_t)4096 * 2048 * 2);
    unsigned char* keep8 = (unsigned char*)alloc(4096);

    cvt_kernel<<<dim3(4096 * 2048 / 4 / 256), dim3(256), 0, stream>>>(x, xb, 4096 * 2048 / 4);
    cvt_kernel<<<dim3(6144 * 2048 / 4 / 256), dim3(256), 0, stream>>>(w_qkv, wqkvb, 6144 * 2048 / 4);
    cvt_kernel<<<dim3(2048 * 2048 / 4 / 256), dim3(256), 0, stream>>>(w_out, woutb, 2048 * 2048 / 4);
    mask_prep<<<dim3(16), dim3(256), 0, stream>>>(maskraw, keep8, 4096);

    gemm_bt<0><<<dim3(48, 32), dim3(256), 0, stream>>>(xb, wqkvb, 4096, 6144, 2048,
                                                       qB, kB, vB, nullptr);
    rope_kernel<<<dim3(131072 / 4), dim3(256), 0, stream>>>(qB, cosp, sinp);
    attn_kernel<<<dim3(16, 32), dim3(256), 0, stream>>>(qB, kB, vB, keep8, attno);
    gemm_bt<1><<<dim3(16, 32), dim3(256), 0, stream>>>(attno, woutb, 4096, 2048, 2048,
                                                       nullptr, nullptr, nullptr, out);
}

// Round 2
// 431.066 us; speedup vs baseline: 1.0664x; 1.0664x over previous
//
#include <hip/hip_runtime.h>

typedef unsigned short u16;
typedef u16 u16x8 __attribute__((ext_vector_type(8)));
typedef u16 u16x4 __attribute__((ext_vector_type(4)));
typedef __bf16 bf16x8_t __attribute__((ext_vector_type(8)));
typedef float f32x4 __attribute__((ext_vector_type(4)));

#define GLOBAL_AS __attribute__((address_space(1)))
#define LDS_AS __attribute__((address_space(3)))

__device__ __forceinline__ float bf2f(u16 v) {
    return __uint_as_float(((unsigned int)v) << 16);
}
__device__ __forceinline__ u16 f2bf(float f) {
    unsigned int u = __float_as_uint(f);
    u += 0x7fff + ((u >> 16) & 1);   // RTNE (no NaNs in this pipeline)
    return (u16)(u >> 16);
}

__device__ __forceinline__ f32x4 mfma_bf16(u16x8 a, u16x8 b, f32x4 c) {
    return __builtin_amdgcn_mfma_f32_16x16x32_bf16(
        __builtin_bit_cast(bf16x8_t, a), __builtin_bit_cast(bf16x8_t, b), c, 0, 0, 0);
}

// ---------------- fp32 -> bf16 convert ----------------
__global__ __launch_bounds__(256) void cvt_kernel(const float* __restrict__ in,
                                                  u16* __restrict__ out, int n4) {
    int i = blockIdx.x * 256 + threadIdx.x;
    if (i >= n4) return;
    float4 f = ((const float4*)in)[i];
    u16x4 o = { f2bf(f.x), f2bf(f.y), f2bf(f.z), f2bf(f.w) };
    ((u16x4*)out)[i] = o;
}

// ---------------- keep-mask -> per-batch length (mask is a prefix mask) ----------------
// mask[0][0] and mask[0][1] are guaranteed true (lengths >= L/2 = 1024).
__global__ __launch_bounds__(256) void mask_prep(const unsigned char* __restrict__ raw,
                                                 int* __restrict__ lens) {
    const int b = blockIdx.x;
    const int tid = threadIdx.x, lane = tid & 63, wid = tid >> 6;
    const unsigned char b0 = raw[0];
    int cnt = 0;
    for (int i = tid; i < 2048; i += 256) {
        const size_t idx = (size_t)b * 2048 + i;
        bool v;
        if (b0 == 0) {                       // fp32 (1.0f -> bytes 00 00 80 3f)
            v = ((const float*)raw)[idx] != 0.0f;
        } else if (b0 == 0x80) {             // bf16 (1.0 -> 0x3F80)
            v = ((const u16*)raw)[idx] != 0;
        } else {                             // integer of width 1/2/4/8
            const int stride = raw[1] ? 1 : (raw[2] ? 2 : (raw[4] ? 4 : 8));
            v = raw[idx * stride] != 0;
        }
        cnt += v ? 1 : 0;
    }
    cnt += __shfl_xor(cnt, 1);
    cnt += __shfl_xor(cnt, 2);
    cnt += __shfl_xor(cnt, 4);
    cnt += __shfl_xor(cnt, 8);
    cnt += __shfl_xor(cnt, 16);
    cnt += __shfl_xor(cnt, 32);
    __shared__ int wsum[4];
    if (lane == 0) wsum[wid] = cnt;
    __syncthreads();
    if (tid == 0) lens[b] = wsum[0] + wsum[1] + wsum[2] + wsum[3];
}

// ---------------- 128x128 bf16 GEMM, C = A(MxK) * B(NxK)^T ----------------
// MODE 0: scatter to q/k/v (B,H,L,hd) bf16.  MODE 1: fp32 out[M][N].
template <int MODE>
__global__ __launch_bounds__(256, 2) void gemm_bt(
    const u16* __restrict__ A, const u16* __restrict__ B,
    int M, int N, int K,
    u16* __restrict__ qp, u16* __restrict__ kp, u16* __restrict__ vp,
    float* __restrict__ outf) {
    __shared__ u16 lA[128 * 64];
    __shared__ u16 lB[128 * 64];
    const int tid  = threadIdx.x;
    const int lane = tid & 63;
    const int wid  = tid >> 6;
    const int wr   = wid >> 1, wc = wid & 1;
    const int brow = blockIdx.y * 128;
    const int bcol = blockIdx.x * 128;

    f32x4 acc[4][4];
#pragma unroll
    for (int m = 0; m < 4; ++m)
#pragma unroll
        for (int n = 0; n < 4; ++n)
            acc[m][n] = (f32x4){0.f, 0.f, 0.f, 0.f};

    const int r0 = tid >> 3;          // staging row within 32-row slab
    const int c0 = (tid & 7) * 16;    // staging byte-col within 128B row

    const int nkt = K >> 6;
    for (int kt = 0; kt < nkt; ++kt) {
#pragma unroll
        for (int i = 0; i < 4; ++i) {
            const int row = i * 32 + r0;
            const u16* ga = A + (size_t)(brow + row) * K + kt * 64 + (c0 >> 1);
            const u16* gb = B + (size_t)(bcol + row) * K + kt * 64 + (c0 >> 1);
            __builtin_amdgcn_global_load_lds((const GLOBAL_AS void*)ga,
                (LDS_AS void*)((char*)lA + i * 4096 + wid * 1024), 16, 0, 0);
            __builtin_amdgcn_global_load_lds((const GLOBAL_AS void*)gb,
                (LDS_AS void*)((char*)lB + i * 4096 + wid * 1024), 16, 0, 0);
        }
        __syncthreads();
#pragma unroll
        for (int ks = 0; ks < 2; ++ks) {
            u16x8 af[4], bfv[4];
#pragma unroll
            for (int m = 0; m < 4; ++m)
                af[m] = *(const u16x8*)&lA[(wr * 64 + m * 16 + (lane & 15)) * 64 + ks * 32 + (lane >> 4) * 8];
#pragma unroll
            for (int n = 0; n < 4; ++n)
                bfv[n] = *(const u16x8*)&lB[(wc * 64 + n * 16 + (lane & 15)) * 64 + ks * 32 + (lane >> 4) * 8];
#pragma unroll
            for (int m = 0; m < 4; ++m)
#pragma unroll
                for (int n = 0; n < 4; ++n)
                    acc[m][n] = mfma_bf16(af[m], bfv[n], acc[m][n]);
        }
        __syncthreads();
    }

#pragma unroll
    for (int m = 0; m < 4; ++m) {
#pragma unroll
        for (int n = 0; n < 4; ++n) {
#pragma unroll
            for (int j = 0; j < 4; ++j) {
                const int row = brow + wr * 64 + m * 16 + (lane >> 4) * 4 + j;
                const int col = bcol + wc * 64 + n * 16 + (lane & 15);
                const float val = acc[m][n][j];
                if (MODE == 0) {
                    const int part = col >> 11;
                    const int e = col & 2047;
                    const int hh = e >> 7, dd = e & 127;
                    const int bb = row >> 11, ll = row & 2047;
                    u16* dst = (part == 0) ? qp : (part == 1) ? kp : vp;
                    dst[((size_t)(bb * 16 + hh) * 2048 + ll) * 128 + dd] = f2bf(val);
                } else {
                    outf[(size_t)row * N + col] = val;
                }
            }
        }
    }
}

// ---------------- RoPE in-place on q,k (contiguous, (2*B*H*L) rows of 128) ----------------
__global__ __launch_bounds__(256) void rope_kernel(u16* __restrict__ qk,
                                                   const float* __restrict__ cosp,
                                                   const float* __restrict__ sinp) {
    const int gid  = blockIdx.x * 4 + (threadIdx.x >> 6);   // row index
    const int lane = threadIdx.x & 63;
    const int l    = gid & 2047;
    u16* row = qk + (size_t)gid * 128;
    const int d1 = lane, d2 = lane + 64;
    const float v1 = bf2f(row[d1]);
    const float v2 = bf2f(row[d2]);
    const float c1 = cosp[l * 128 + d1], s1 = sinp[l * 128 + d1];
    const float c2 = cosp[l * 128 + d2], s2 = sinp[l * 128 + d2];
    row[d1] = f2bf(v1 * c1 - v2 * s1);   // rot_half: -t[d+64] for d<64
    row[d2] = f2bf(v2 * c2 + v1 * s2);   //           +t[d-64] for d>=64
}

// ---------------- flash attention: causal + prefix key-padding mask ----------------
// Balanced pairing: block jA handles q-tiles jA and 31-jA (64 rows each) ->
// every block does exactly 33 KV-tile units. grid (16, 32), 256 threads (4 waves).
// Each wave owns 16 q-rows of each tile. K/V reg-prefetched (T14).
__global__ __launch_bounds__(256, 2) void attn_kernel(
    const u16* __restrict__ Q, const u16* __restrict__ K, const u16* __restrict__ V,
    const int* __restrict__ lens, u16* __restrict__ O) {
    __shared__ u16 lK[64 * 136];    // K tile, padded row stride 136
    __shared__ u16 lVT[128 * 72];   // V transposed: [d][key], stride 72
    __shared__ u16 lP[4 * 16 * 72]; // per-wave P: [16 q][keys], stride 72

    const int tid = threadIdx.x, lane = tid & 63, wid = tid >> 6;
    const int jA = blockIdx.x;       // 0..15
    const int jB = 31 - jA;          // 16..31
    const int bh = blockIdx.y;
    const int b  = bh >> 4;
    const int h  = bh & 15;
    const u16* qb = Q + (size_t)bh * 2048 * 128;
    const u16* kb = K + (size_t)bh * 2048 * 128;
    const u16* vb = V + (size_t)bh * 2048 * 128;
    const int lenb = lens[b];
    const int q0A = jA * 64 + wid * 16;
    const int q0B = jB * 64 + wid * 16;
    const int srow = lane;           // staging row 0..63 within tid: need 0..63 x 4 chunks
    const int str  = tid & 63;
    const int sdc  = tid >> 6;       // d-chunk 0..3 (32 d each)
    const float scale = 0.08838834764831845f;  // 1/sqrt(128)
    u16* lPw = lP + wid * (16 * 72);

    // Q fragments in registers (already RoPE'd)
    u16x8 aqA[4], aqB[4];
#pragma unroll
    for (int kc = 0; kc < 4; ++kc) {
        aqA[kc] = *(const u16x8*)(qb + (size_t)(q0A + (lane & 15)) * 128 + kc * 32 + (lane >> 4) * 8);
        aqB[kc] = *(const u16x8*)(qb + (size_t)(q0B + (lane & 15)) * 128 + kc * 32 + (lane >> 4) * 8);
    }

    float msA[4], lsA[4], msB[4], lsB[4];
    f32x4 aoA[8], aoB[8];
#pragma unroll
    for (int j = 0; j < 4; ++j) { msA[j] = -1e30f; lsA[j] = 0.f; msB[j] = -1e30f; lsB[j] = 0.f; }
#pragma unroll
    for (int n = 0; n < 8; ++n) { aoA[n] = (f32x4){0.f,0.f,0.f,0.f}; aoB[n] = (f32x4){0.f,0.f,0.f,0.f}; }

    auto ldregs = [&](int t, u16x8 (&pk)[4], u16x8 (&pv)[4]) {
        const u16* ks = kb + (size_t)(t * 64 + str) * 128 + sdc * 32;
        const u16* vs = vb + (size_t)(t * 64 + str) * 128 + sdc * 32;
#pragma unroll
        for (int i = 0; i < 4; ++i) {
            pk[i] = *(const u16x8*)(ks + i * 8);
            pv[i] = *(const u16x8*)(vs + i * 8);
        }
    };
    auto stw = [&](u16x8 (&pk)[4], u16x8 (&pv)[4]) {
#pragma unroll
        for (int i = 0; i < 4; ++i) {
            *(u16x8*)&lK[str * 136 + sdc * 32 + i * 8] = pk[i];
#pragma unroll
            for (int e = 0; e < 8; ++e)
                lVT[(sdc * 32 + i * 8 + e) * 72 + str] = pv[i][e];
        }
    };

    auto process = [&](int q0w, u16x8 (&aq)[4], float (&ms)[4], float (&ls)[4],
                       f32x4 (&ao)[8], int kv0, bool diag) {
        // ---- S = Q K^T ----
        f32x4 s[4];
#pragma unroll
        for (int n = 0; n < 4; ++n) s[n] = (f32x4){0.f,0.f,0.f,0.f};
#pragma unroll
        for (int kc = 0; kc < 4; ++kc) {
            u16x8 bk[4];
#pragma unroll
            for (int n = 0; n < 4; ++n)
                bk[n] = *(const u16x8*)&lK[(n * 16 + (lane & 15)) * 136 + kc * 32 + (lane >> 4) * 8];
#pragma unroll
            for (int n = 0; n < 4; ++n)
                s[n] = mfma_bf16(aq[kc], bk[n], s[n]);
        }
        // ---- masked online softmax (fp32, scale fused into exp) ----
        const bool needmask = diag || (kv0 + 64 > lenb);
#pragma unroll
        for (int j = 0; j < 4; ++j) {
            const int row = (lane >> 4) * 4 + j;
            float sv[4];
            if (needmask) {
                const int qq = q0w + row;
                const int bound = (qq < lenb - 1) ? qq : (lenb - 1);
#pragma unroll
                for (int n = 0; n < 4; ++n) {
                    const int kk = kv0 + n * 16 + (lane & 15);
                    sv[n] = (kk <= bound) ? s[n][j] : -1e30f;
                }
            } else {
#pragma unroll
                for (int n = 0; n < 4; ++n) sv[n] = s[n][j];
            }
            float rm = fmaxf(fmaxf(sv[0], sv[1]), fmaxf(sv[2], sv[3]));
            rm = fmaxf(rm, __shfl_xor(rm, 1));
            rm = fmaxf(rm, __shfl_xor(rm, 2));
            rm = fmaxf(rm, __shfl_xor(rm, 4));
            rm = fmaxf(rm, __shfl_xor(rm, 8));
            const float mn = fmaxf(ms[j], rm);
            const float alpha = __expf((ms[j] - mn) * scale);
            ms[j] = mn;
            const float mk = mn * scale;
            float rs = 0.f;
#pragma unroll
            for (int n = 0; n < 4; ++n) {
                const float p = __expf(fmaf(sv[n], scale, -mk));
                rs += p;
                lPw[row * 72 + n * 16 + (lane & 15)] = f2bf(p);
            }
            rs += __shfl_xor(rs, 1);
            rs += __shfl_xor(rs, 2);
            rs += __shfl_xor(rs, 4);
            rs += __shfl_xor(rs, 8);
            ls[j] = fmaf(ls[j], alpha, rs);
#pragma unroll
            for (int n = 0; n < 8; ++n) ao[n][j] *= alpha;
        }
        // ---- O += P V ----
#pragma unroll
        for (int kc = 0; kc < 2; ++kc) {
            u16x8 ap = *(const u16x8*)&lPw[(lane & 15) * 72 + kc * 32 + (lane >> 4) * 8];
#pragma unroll
            for (int n = 0; n < 8; ++n) {
                u16x8 bv = *(const u16x8*)&lVT[(n * 16 + (lane & 15)) * 72 + kc * 32 + (lane >> 4) * 8];
                ao[n] = mfma_bf16(ap, bv, ao[n]);
            }
        }
    };

    const int nt = jB + 1;   // 17..32 KV tiles; subtile A active for t <= jA

    // prologue: stage tile 0
    {
        u16x8 pk[4], pv[4];
        ldregs(0, pk, pv);
        stw(pk, pv);
    }
    __syncthreads();

    for (int t = 0; t < nt; ++t) {
        u16x8 pk[4], pv[4];
        const bool pf = (t + 1 < nt);
        if (pf) ldregs(t + 1, pk, pv);          // T14: issue loads before compute
        process(q0B, aqB, msB, lsB, aoB, t * 64, t == jB);
        if (t <= jA)
            process(q0A, aqA, msA, lsA, aoA, t * 64, t == jA);
        if (pf) {
            __syncthreads();                    // all waves done reading lK/lVT
            stw(pk, pv);
            __syncthreads();                    // next tile staged
        }
    }

    // ---- epilogue: normalize, row-mask, write (B,L,D) ----
#pragma unroll
    for (int j = 0; j < 4; ++j) {
        const int qqA = q0A + (lane >> 4) * 4 + j;
        const int qqB = q0B + (lane >> 4) * 4 + j;
        const float invA = (qqA < lenb) ? (1.f / lsA[j]) : 0.f;
        const float invB = (qqB < lenb) ? (1.f / lsB[j]) : 0.f;
#pragma unroll
        for (int n = 0; n < 8; ++n) {
            const int d = n * 16 + (lane & 15);
            O[((size_t)b * 2048 + qqA) * 2048 + h * 128 + d] = f2bf(aoA[n][j] * invA);
            O[((size_t)b * 2048 + qqB) * 2048 + h * 128 + d] = f2bf(aoB[n][j] * invB);
        }
    }
}

// ---------------- launch ----------------
extern "C" void kernel_launch(void* const* d_in, const int* in_sizes, int n_in,
                              void* d_out, int out_size, void* d_ws, size_t ws_size,
                              hipStream_t stream) {
    const float* x      = (const float*)d_in[0];
    const unsigned char* maskraw = (const unsigned char*)d_in[1];
    const float* cosp   = (const float*)d_in[2];
    const float* sinp   = (const float*)d_in[3];
    const float* w_qkv  = (const float*)d_in[4];
    const float* w_out  = (const float*)d_in[5];
    float* out = (float*)d_out;

    char* ws = (char*)d_ws;
    size_t off = 0;
    auto alloc = [&](size_t bytes) {
        char* p = ws + off;
        off += (bytes + 255) & ~(size_t)255;
        return p;
    };
    u16* xb    = (u16*)alloc((size_t)4096 * 2048 * 2);
    u16* wqkvb = (u16*)alloc((size_t)6144 * 2048 * 2);
    u16* woutb = (u16*)alloc((size_t)2048 * 2048 * 2);
    u16* qB    = (u16*)alloc((size_t)65536 * 128 * 2);  // (B,H,L,hd)
    u16* kB    = (u16*)alloc((size_t)65536 * 128 * 2);  // contiguous after qB (rope relies on it)
    u16* vB    = (u16*)alloc((size_t)65536 * 128 * 2);
    u16* attno = (u16*)alloc((size_t)4096 * 2048 * 2);
    int* lens  = (int*)alloc(256);

    cvt_kernel<<<dim3(4096 * 2048 / 4 / 256), dim3(256), 0, stream>>>(x, xb, 4096 * 2048 / 4);
    cvt_kernel<<<dim3(6144 * 2048 / 4 / 256), dim3(256), 0, stream>>>(w_qkv, wqkvb, 6144 * 2048 / 4);
    cvt_kernel<<<dim3(2048 * 2048 / 4 / 256), dim3(256), 0, stream>>>(w_out, woutb, 2048 * 2048 / 4);
    mask_prep<<<dim3(2), dim3(256), 0, stream>>>(maskraw, lens);

    gemm_bt<0><<<dim3(48, 32), dim3(256), 0, stream>>>(xb, wqkvb, 4096, 6144, 2048,
                                                       qB, kB, vB, nullptr);
    rope_kernel<<<dim3(131072 / 4), dim3(256), 0, stream>>>(qB, cosp, sinp);
    attn_kernel<<<dim3(16, 32), dim3(256), 0, stream>>>(qB, kB, vB, lens, attno);
    gemm_bt<1><<<dim3(16, 32), dim3(256), 0, stream>>>(attno, woutb, 4096, 2048, 2048,
                                                       nullptr, nullptr, nullptr, out);
}

// Round 3
// 332.533 us; speedup vs baseline: 1.3824x; 1.2963x over previous
//
#include <hip/hip_runtime.h>

typedef unsigned short u16;
typedef u16 u16x8 __attribute__((ext_vector_type(8)));
typedef u16 u16x4 __attribute__((ext_vector_type(4)));
typedef __bf16 bf16x8_t __attribute__((ext_vector_type(8)));
typedef float f32x4 __attribute__((ext_vector_type(4)));

#define GLOBAL_AS __attribute__((address_space(1)))
#define LDS_AS __attribute__((address_space(3)))

__device__ __forceinline__ float bf2f(u16 v) {
    return __uint_as_float(((unsigned int)v) << 16);
}
__device__ __forceinline__ u16 f2bf(float f) {
    unsigned int u = __float_as_uint(f);
    u += 0x7fff + ((u >> 16) & 1);   // RTNE (no NaNs in this pipeline)
    return (u16)(u >> 16);
}

__device__ __forceinline__ f32x4 mfma_bf16(u16x8 a, u16x8 b, f32x4 c) {
    return __builtin_amdgcn_mfma_f32_16x16x32_bf16(
        __builtin_bit_cast(bf16x8_t, a), __builtin_bit_cast(bf16x8_t, b), c, 0, 0, 0);
}

// ---------------- fp32 -> bf16 convert ----------------
__global__ __launch_bounds__(256) void cvt_kernel(const float* __restrict__ in,
                                                  u16* __restrict__ out, int n4) {
    int i = blockIdx.x * 256 + threadIdx.x;
    if (i >= n4) return;
    float4 f = ((const float4*)in)[i];
    u16x4 o = { f2bf(f.x), f2bf(f.y), f2bf(f.z), f2bf(f.w) };
    ((u16x4*)out)[i] = o;
}

// ---------------- keep-mask -> per-batch length (mask is a prefix mask) ----------------
__global__ __launch_bounds__(256) void mask_prep(const unsigned char* __restrict__ raw,
                                                 int* __restrict__ lens) {
    const int b = blockIdx.x;
    const int tid = threadIdx.x, lane = tid & 63, wid = tid >> 6;
    const unsigned char b0 = raw[0];
    int cnt = 0;
    for (int i = tid; i < 2048; i += 256) {
        const size_t idx = (size_t)b * 2048 + i;
        bool v;
        if (b0 == 0) {                       // fp32 (1.0f -> bytes 00 00 80 3f)
            v = ((const float*)raw)[idx] != 0.0f;
        } else if (b0 == 0x80) {             // bf16 (1.0 -> 0x3F80)
            v = ((const u16*)raw)[idx] != 0;
        } else {                             // integer of width 1/2/4/8
            const int stride = raw[1] ? 1 : (raw[2] ? 2 : (raw[4] ? 4 : 8));
            v = raw[idx * stride] != 0;
        }
        cnt += v ? 1 : 0;
    }
    cnt += __shfl_xor(cnt, 1);
    cnt += __shfl_xor(cnt, 2);
    cnt += __shfl_xor(cnt, 4);
    cnt += __shfl_xor(cnt, 8);
    cnt += __shfl_xor(cnt, 16);
    cnt += __shfl_xor(cnt, 32);
    __shared__ int wsum[4];
    if (lane == 0) wsum[wid] = cnt;
    __syncthreads();
    if (tid == 0) lens[b] = wsum[0] + wsum[1] + wsum[2] + wsum[3];
}

// ---------------- 128x128 bf16 GEMM, C = A(MxK) * B(NxK)^T ----------------
// MODE 0: scatter to q/k/v (B,H,L,hd) bf16.  MODE 1: fp32 out[M][N].
template <int MODE>
__global__ __launch_bounds__(256, 2) void gemm_bt(
    const u16* __restrict__ A, const u16* __restrict__ B,
    int M, int N, int K,
    u16* __restrict__ qp, u16* __restrict__ kp, u16* __restrict__ vp,
    float* __restrict__ outf) {
    __shared__ u16 lA[128 * 64];
    __shared__ u16 lB[128 * 64];
    const int tid  = threadIdx.x;
    const int lane = tid & 63;
    const int wid  = tid >> 6;
    const int wr   = wid >> 1, wc = wid & 1;
    const int brow = blockIdx.y * 128;
    const int bcol = blockIdx.x * 128;

    f32x4 acc[4][4];
#pragma unroll
    for (int m = 0; m < 4; ++m)
#pragma unroll
        for (int n = 0; n < 4; ++n)
            acc[m][n] = (f32x4){0.f, 0.f, 0.f, 0.f};

    const int r0 = tid >> 3;          // staging row within 32-row slab
    const int c0 = (tid & 7) * 16;    // staging byte-col within 128B row

    const int nkt = K >> 6;
    for (int kt = 0; kt < nkt; ++kt) {
#pragma unroll
        for (int i = 0; i < 4; ++i) {
            const int row = i * 32 + r0;
            const u16* ga = A + (size_t)(brow + row) * K + kt * 64 + (c0 >> 1);
            const u16* gb = B + (size_t)(bcol + row) * K + kt * 64 + (c0 >> 1);
            __builtin_amdgcn_global_load_lds((const GLOBAL_AS void*)ga,
                (LDS_AS void*)((char*)lA + i * 4096 + wid * 1024), 16, 0, 0);
            __builtin_amdgcn_global_load_lds((const GLOBAL_AS void*)gb,
                (LDS_AS void*)((char*)lB + i * 4096 + wid * 1024), 16, 0, 0);
        }
        __syncthreads();
#pragma unroll
        for (int ks = 0; ks < 2; ++ks) {
            u16x8 af[4], bfv[4];
#pragma unroll
            for (int m = 0; m < 4; ++m)
                af[m] = *(const u16x8*)&lA[(wr * 64 + m * 16 + (lane & 15)) * 64 + ks * 32 + (lane >> 4) * 8];
#pragma unroll
            for (int n = 0; n < 4; ++n)
                bfv[n] = *(const u16x8*)&lB[(wc * 64 + n * 16 + (lane & 15)) * 64 + ks * 32 + (lane >> 4) * 8];
#pragma unroll
            for (int m = 0; m < 4; ++m)
#pragma unroll
                for (int n = 0; n < 4; ++n)
                    acc[m][n] = mfma_bf16(af[m], bfv[n], acc[m][n]);
        }
        __syncthreads();
    }

#pragma unroll
    for (int m = 0; m < 4; ++m) {
#pragma unroll
        for (int n = 0; n < 4; ++n) {
#pragma unroll
            for (int j = 0; j < 4; ++j) {
                const int row = brow + wr * 64 + m * 16 + (lane >> 4) * 4 + j;
                const int col = bcol + wc * 64 + n * 16 + (lane & 15);
                const float val = acc[m][n][j];
                if (MODE == 0) {
                    const int part = col >> 11;
                    const int e = col & 2047;
                    const int hh = e >> 7, dd = e & 127;
                    const int bb = row >> 11, ll = row & 2047;
                    u16* dst = (part == 0) ? qp : (part == 1) ? kp : vp;
                    dst[((size_t)(bb * 16 + hh) * 2048 + ll) * 128 + dd] = f2bf(val);
                } else {
                    outf[(size_t)row * N + col] = val;
                }
            }
        }
    }
}

// ---------------- RoPE in-place on q,k (contiguous, (2*B*H*L) rows of 128) ----------------
__global__ __launch_bounds__(256) void rope_kernel(u16* __restrict__ qk,
                                                   const float* __restrict__ cosp,
                                                   const float* __restrict__ sinp) {
    const int gid  = blockIdx.x * 4 + (threadIdx.x >> 6);   // row index
    const int lane = threadIdx.x & 63;
    const int l    = gid & 2047;
    u16* row = qk + (size_t)gid * 128;
    const int d1 = lane, d2 = lane + 64;
    const float v1 = bf2f(row[d1]);
    const float v2 = bf2f(row[d2]);
    const float c1 = cosp[l * 128 + d1], s1 = sinp[l * 128 + d1];
    const float c2 = cosp[l * 128 + d2], s2 = sinp[l * 128 + d2];
    row[d1] = f2bf(v1 * c1 - v2 * s1);   // rot_half: -t[d+64] for d<64
    row[d2] = f2bf(v2 * c2 + v1 * s2);   //           +t[d-64] for d>=64
}

// ---------------- flash attention: causal + prefix key-padding mask ----------------
// Balanced pairing, SEQUENTIAL halves (one live accumulator set -> no spills):
// block handles q-tile jB=31-jA (tiles 0..jB) then q-tile jA (tiles 0..jA):
// exactly 34 staged KV tiles per block. grid(512), 4 waves, 16 q-rows/wave/half.
// Block id -> (jA, bh) mapped so XCD k hosts bh in {4k..4k+3}: per-XCD K/V
// working set = 4 MB = one L2.
__global__ __launch_bounds__(256, 2) void attn_kernel(
    const u16* __restrict__ Q, const u16* __restrict__ K, const u16* __restrict__ V,
    const int* __restrict__ lens, u16* __restrict__ O) {
    __shared__ u16 lK[64 * 136];    // K tile, padded row stride 136
    __shared__ u16 lVT[128 * 72];   // V transposed: [d][key], stride 72
    __shared__ u16 lP[4 * 16 * 72]; // per-wave P: [16 q][keys], stride 72

    const int tid = threadIdx.x, lane = tid & 63, wid = tid >> 6;
    const int g   = blockIdx.x;
    const int xcd = g & 7;
    const int s   = g >> 3;
    const int jA  = s >> 2;                 // 0..15
    const int bh  = (xcd << 2) | (s & 3);   // 0..31, clustered per XCD
    const int b   = bh >> 4;
    const int h   = bh & 15;
    const u16* qb = Q + (size_t)bh * 2048 * 128;
    const u16* kb = K + (size_t)bh * 2048 * 128;
    const u16* vb = V + (size_t)bh * 2048 * 128;
    const int lenb = lens[b];
    const int str = lane;            // staging row 0..63
    const int sdc = wid;             // staging d-chunk 0..3 (32 d each)
    const float scale = 0.08838834764831845f;  // 1/sqrt(128)
    u16* lPw = lP + wid * (16 * 72);

    for (int half = 0; half < 2; ++half) {
        const int jq = half ? jA : (31 - jA);
        const int q0w = jq * 64 + wid * 16;
        const int nt = jq + 1;

        // Q fragments in registers (already RoPE'd)
        u16x8 aq[4];
#pragma unroll
        for (int kc = 0; kc < 4; ++kc)
            aq[kc] = *(const u16x8*)(qb + (size_t)(q0w + (lane & 15)) * 128 + kc * 32 + (lane >> 4) * 8);

        float ms[4], ls[4];
        f32x4 ao[8];
#pragma unroll
        for (int j = 0; j < 4; ++j) { ms[j] = -1e30f; ls[j] = 0.f; }
#pragma unroll
        for (int n = 0; n < 8; ++n) ao[n] = (f32x4){0.f, 0.f, 0.f, 0.f};

        u16x8 pk[4], pv[4];
        // prologue: stage tile 0
        {
            const u16* ks = kb + (size_t)str * 128 + sdc * 32;
            const u16* vs = vb + (size_t)str * 128 + sdc * 32;
#pragma unroll
            for (int i = 0; i < 4; ++i) { pk[i] = *(const u16x8*)(ks + i * 8); pv[i] = *(const u16x8*)(vs + i * 8); }
        }
        __syncthreads();   // previous half's LDS reads complete before overwrite
#pragma unroll
        for (int i = 0; i < 4; ++i) {
            *(u16x8*)&lK[str * 136 + sdc * 32 + i * 8] = pk[i];
#pragma unroll
            for (int e = 0; e < 8; ++e)
                lVT[(sdc * 32 + i * 8 + e) * 72 + str] = pv[i][e];
        }
        __syncthreads();

        for (int t = 0; t < nt; ++t) {
            const bool pf = (t + 1 < nt);
            if (pf) {   // T14: issue next-tile loads before compute
                const u16* ks = kb + (size_t)((t + 1) * 64 + str) * 128 + sdc * 32;
                const u16* vs = vb + (size_t)((t + 1) * 64 + str) * 128 + sdc * 32;
#pragma unroll
                for (int i = 0; i < 4; ++i) { pk[i] = *(const u16x8*)(ks + i * 8); pv[i] = *(const u16x8*)(vs + i * 8); }
            }
            const int kv0 = t * 64;

            // ---- S = Q K^T ----
            f32x4 sv4[4];
#pragma unroll
            for (int n = 0; n < 4; ++n) sv4[n] = (f32x4){0.f, 0.f, 0.f, 0.f};
#pragma unroll
            for (int kc = 0; kc < 4; ++kc) {
                u16x8 bk[4];
#pragma unroll
                for (int n = 0; n < 4; ++n)
                    bk[n] = *(const u16x8*)&lK[(n * 16 + (lane & 15)) * 136 + kc * 32 + (lane >> 4) * 8];
#pragma unroll
                for (int n = 0; n < 4; ++n)
                    sv4[n] = mfma_bf16(aq[kc], bk[n], sv4[n]);
            }

            // ---- masked online softmax (fp32, scale fused into exp) ----
            const bool needmask = (t == jq) || (kv0 + 64 > lenb);
#pragma unroll
            for (int j = 0; j < 4; ++j) {
                const int row = (lane >> 4) * 4 + j;
                float sv[4];
                if (needmask) {
                    const int qq = q0w + row;
                    const int bound = (qq < lenb - 1) ? qq : (lenb - 1);
#pragma unroll
                    for (int n = 0; n < 4; ++n) {
                        const int kk = kv0 + n * 16 + (lane & 15);
                        sv[n] = (kk <= bound) ? sv4[n][j] : -1e30f;
                    }
                } else {
#pragma unroll
                    for (int n = 0; n < 4; ++n) sv[n] = sv4[n][j];
                }
                float rm = fmaxf(fmaxf(sv[0], sv[1]), fmaxf(sv[2], sv[3]));
                rm = fmaxf(rm, __shfl_xor(rm, 1));
                rm = fmaxf(rm, __shfl_xor(rm, 2));
                rm = fmaxf(rm, __shfl_xor(rm, 4));
                rm = fmaxf(rm, __shfl_xor(rm, 8));
                const float mn = fmaxf(ms[j], rm);
                const float alpha = __expf((ms[j] - mn) * scale);
                ms[j] = mn;
                const float mk = mn * scale;
                float rs = 0.f;
#pragma unroll
                for (int n = 0; n < 4; ++n) {
                    const float p = __expf(fmaf(sv[n], scale, -mk));
                    rs += p;
                    lPw[row * 72 + n * 16 + (lane & 15)] = f2bf(p);
                }
                rs += __shfl_xor(rs, 1);
                rs += __shfl_xor(rs, 2);
                rs += __shfl_xor(rs, 4);
                rs += __shfl_xor(rs, 8);
                ls[j] = fmaf(ls[j], alpha, rs);
#pragma unroll
                for (int n = 0; n < 8; ++n) ao[n][j] *= alpha;
            }

            // ---- O += P V ----
#pragma unroll
            for (int kc = 0; kc < 2; ++kc) {
                u16x8 ap = *(const u16x8*)&lPw[(lane & 15) * 72 + kc * 32 + (lane >> 4) * 8];
#pragma unroll
                for (int n = 0; n < 8; ++n) {
                    u16x8 bv = *(const u16x8*)&lVT[(n * 16 + (lane & 15)) * 72 + kc * 32 + (lane >> 4) * 8];
                    ao[n] = mfma_bf16(ap, bv, ao[n]);
                }
            }

            if (pf) {
                __syncthreads();   // all waves done reading lK/lVT
#pragma unroll
                for (int i = 0; i < 4; ++i) {
                    *(u16x8*)&lK[str * 136 + sdc * 32 + i * 8] = pk[i];
#pragma unroll
                    for (int e = 0; e < 8; ++e)
                        lVT[(sdc * 32 + i * 8 + e) * 72 + str] = pv[i][e];
                }
                __syncthreads();   // next tile staged
            }
        }

        // ---- epilogue: normalize, row-mask, write (B,L,D) ----
#pragma unroll
        for (int j = 0; j < 4; ++j) {
            const int qq = q0w + (lane >> 4) * 4 + j;
            const float inv = (qq < lenb) ? (1.f / ls[j]) : 0.f;
#pragma unroll
            for (int n = 0; n < 8; ++n) {
                const int d = n * 16 + (lane & 15);
                O[((size_t)b * 2048 + qq) * 2048 + h * 128 + d] = f2bf(ao[n][j] * inv);
            }
        }
    }
}

// ---------------- launch ----------------
extern "C" void kernel_launch(void* const* d_in, const int* in_sizes, int n_in,
                              void* d_out, int out_size, void* d_ws, size_t ws_size,
                              hipStream_t stream) {
    const float* x      = (const float*)d_in[0];
    const unsigned char* maskraw = (const unsigned char*)d_in[1];
    const float* cosp   = (const float*)d_in[2];
    const float* sinp   = (const float*)d_in[3];
    const float* w_qkv  = (const float*)d_in[4];
    const float* w_out  = (const float*)d_in[5];
    float* out = (float*)d_out;

    char* ws = (char*)d_ws;
    size_t off = 0;
    auto alloc = [&](size_t bytes) {
        char* p = ws + off;
        off += (bytes + 255) & ~(size_t)255;
        return p;
    };
    u16* xb    = (u16*)alloc((size_t)4096 * 2048 * 2);
    u16* wqkvb = (u16*)alloc((size_t)6144 * 2048 * 2);
    u16* woutb = (u16*)alloc((size_t)2048 * 2048 * 2);
    u16* qB    = (u16*)alloc((size_t)65536 * 128 * 2);  // (B,H,L,hd)
    u16* kB    = (u16*)alloc((size_t)65536 * 128 * 2);  // contiguous after qB (rope relies on it)
    u16* vB    = (u16*)alloc((size_t)65536 * 128 * 2);
    u16* attno = (u16*)alloc((size_t)4096 * 2048 * 2);
    int* lens  = (int*)alloc(256);

    cvt_kernel<<<dim3(4096 * 2048 / 4 / 256), dim3(256), 0, stream>>>(x, xb, 4096 * 2048 / 4);
    cvt_kernel<<<dim3(6144 * 2048 / 4 / 256), dim3(256), 0, stream>>>(w_qkv, wqkvb, 6144 * 2048 / 4);
    cvt_kernel<<<dim3(2048 * 2048 / 4 / 256), dim3(256), 0, stream>>>(w_out, woutb, 2048 * 2048 / 4);
    mask_prep<<<dim3(2), dim3(256), 0, stream>>>(maskraw, lens);

    gemm_bt<0><<<dim3(48, 32), dim3(256), 0, stream>>>(xb, wqkvb, 4096, 6144, 2048,
                                                       qB, kB, vB, nullptr);
    rope_kernel<<<dim3(131072 / 4), dim3(256), 0, stream>>>(qB, cosp, sinp);
    attn_kernel<<<dim3(512), dim3(256), 0, stream>>>(qB, kB, vB, lens, attno);
    gemm_bt<1><<<dim3(16, 32), dim3(256), 0, stream>>>(attno, woutb, 4096, 2048, 2048,
                                                       nullptr, nullptr, nullptr, out);
}

// Round 4
// 321.220 us; speedup vs baseline: 1.4311x; 1.0352x over previous
//
#include <hip/hip_runtime.h>

typedef unsigned short u16;
typedef u16 u16x8 __attribute__((ext_vector_type(8)));
typedef u16 u16x4 __attribute__((ext_vector_type(4)));
typedef __bf16 bf16x8_t __attribute__((ext_vector_type(8)));
typedef float f32x4 __attribute__((ext_vector_type(4)));

#define GLOBAL_AS __attribute__((address_space(1)))
#define LDS_AS __attribute__((address_space(3)))

__device__ __forceinline__ float bf2f(u16 v) {
    return __uint_as_float(((unsigned int)v) << 16);
}
__device__ __forceinline__ u16 f2bf(float f) {
    unsigned int u = __float_as_uint(f);
    u += 0x7fff + ((u >> 16) & 1);   // RTNE (no NaNs in this pipeline)
    return (u16)(u >> 16);
}

__device__ __forceinline__ f32x4 mfma_bf16(u16x8 a, u16x8 b, f32x4 c) {
    return __builtin_amdgcn_mfma_f32_16x16x32_bf16(
        __builtin_bit_cast(bf16x8_t, a), __builtin_bit_cast(bf16x8_t, b), c, 0, 0, 0);
}

// 16-lane (row) reductions via DPP — pure VALU, no LDS pipe.
// quad_perm xor1 (0xB1), xor2 (0x4E), then row_ror:4 (0x124), row_ror:8 (0x128).
__device__ __forceinline__ float red16_max(float x) {
    int t;
    t = __builtin_amdgcn_update_dpp(0, __builtin_bit_cast(int, x), 0xB1, 0xF, 0xF, true);
    x = fmaxf(x, __builtin_bit_cast(float, t));
    t = __builtin_amdgcn_update_dpp(0, __builtin_bit_cast(int, x), 0x4E, 0xF, 0xF, true);
    x = fmaxf(x, __builtin_bit_cast(float, t));
    t = __builtin_amdgcn_update_dpp(0, __builtin_bit_cast(int, x), 0x124, 0xF, 0xF, true);
    x = fmaxf(x, __builtin_bit_cast(float, t));
    t = __builtin_amdgcn_update_dpp(0, __builtin_bit_cast(int, x), 0x128, 0xF, 0xF, true);
    x = fmaxf(x, __builtin_bit_cast(float, t));
    return x;
}
__device__ __forceinline__ float red16_sum(float x) {
    int t;
    t = __builtin_amdgcn_update_dpp(0, __builtin_bit_cast(int, x), 0xB1, 0xF, 0xF, true);
    x += __builtin_bit_cast(float, t);
    t = __builtin_amdgcn_update_dpp(0, __builtin_bit_cast(int, x), 0x4E, 0xF, 0xF, true);
    x += __builtin_bit_cast(float, t);
    t = __builtin_amdgcn_update_dpp(0, __builtin_bit_cast(int, x), 0x124, 0xF, 0xF, true);
    x += __builtin_bit_cast(float, t);
    t = __builtin_amdgcn_update_dpp(0, __builtin_bit_cast(int, x), 0x128, 0xF, 0xF, true);
    x += __builtin_bit_cast(float, t);
    return x;
}

// ---------------- fp32 -> bf16 convert ----------------
__global__ __launch_bounds__(256) void cvt_kernel(const float* __restrict__ in,
                                                  u16* __restrict__ out, int n4) {
    int i = blockIdx.x * 256 + threadIdx.x;
    if (i >= n4) return;
    float4 f = ((const float4*)in)[i];
    u16x4 o = { f2bf(f.x), f2bf(f.y), f2bf(f.z), f2bf(f.w) };
    ((u16x4*)out)[i] = o;
}

// ---------------- keep-mask -> per-batch length (mask is a prefix mask) ----------------
__global__ __launch_bounds__(256) void mask_prep(const unsigned char* __restrict__ raw,
                                                 int* __restrict__ lens) {
    const int b = blockIdx.x;
    const int tid = threadIdx.x, lane = tid & 63, wid = tid >> 6;
    const unsigned char b0 = raw[0];
    int cnt = 0;
    for (int i = tid; i < 2048; i += 256) {
        const size_t idx = (size_t)b * 2048 + i;
        bool v;
        if (b0 == 0) {                       // fp32 (1.0f -> bytes 00 00 80 3f)
            v = ((const float*)raw)[idx] != 0.0f;
        } else if (b0 == 0x80) {             // bf16 (1.0 -> 0x3F80)
            v = ((const u16*)raw)[idx] != 0;
        } else {                             // integer of width 1/2/4/8
            const int stride = raw[1] ? 1 : (raw[2] ? 2 : (raw[4] ? 4 : 8));
            v = raw[idx * stride] != 0;
        }
        cnt += v ? 1 : 0;
    }
    cnt += __shfl_xor(cnt, 1);
    cnt += __shfl_xor(cnt, 2);
    cnt += __shfl_xor(cnt, 4);
    cnt += __shfl_xor(cnt, 8);
    cnt += __shfl_xor(cnt, 16);
    cnt += __shfl_xor(cnt, 32);
    __shared__ int wsum[4];
    if (lane == 0) wsum[wid] = cnt;
    __syncthreads();
    if (tid == 0) lens[b] = wsum[0] + wsum[1] + wsum[2] + wsum[3];
}

// ---------------- 128x128 bf16 GEMM, C = A(MxK) * B(NxK)^T ----------------
// MODE 0: scatter to q/k/v (B,H,L,hd) bf16.  MODE 1: fp32 out[M][N].
template <int MODE>
__global__ __launch_bounds__(256, 2) void gemm_bt(
    const u16* __restrict__ A, const u16* __restrict__ B,
    int M, int N, int K,
    u16* __restrict__ qp, u16* __restrict__ kp, u16* __restrict__ vp,
    float* __restrict__ outf) {
    __shared__ u16 lA[128 * 64];
    __shared__ u16 lB[128 * 64];
    const int tid  = threadIdx.x;
    const int lane = tid & 63;
    const int wid  = tid >> 6;
    const int wr   = wid >> 1, wc = wid & 1;
    const int brow = blockIdx.y * 128;
    const int bcol = blockIdx.x * 128;

    f32x4 acc[4][4];
#pragma unroll
    for (int m = 0; m < 4; ++m)
#pragma unroll
        for (int n = 0; n < 4; ++n)
            acc[m][n] = (f32x4){0.f, 0.f, 0.f, 0.f};

    const int r0 = tid >> 3;          // staging row within 32-row slab
    const int c0 = (tid & 7) * 16;    // staging byte-col within 128B row

    const int nkt = K >> 6;
    for (int kt = 0; kt < nkt; ++kt) {
#pragma unroll
        for (int i = 0; i < 4; ++i) {
            const int row = i * 32 + r0;
            const u16* ga = A + (size_t)(brow + row) * K + kt * 64 + (c0 >> 1);
            const u16* gb = B + (size_t)(bcol + row) * K + kt * 64 + (c0 >> 1);
            __builtin_amdgcn_global_load_lds((const GLOBAL_AS void*)ga,
                (LDS_AS void*)((char*)lA + i * 4096 + wid * 1024), 16, 0, 0);
            __builtin_amdgcn_global_load_lds((const GLOBAL_AS void*)gb,
                (LDS_AS void*)((char*)lB + i * 4096 + wid * 1024), 16, 0, 0);
        }
        __syncthreads();
#pragma unroll
        for (int ks = 0; ks < 2; ++ks) {
            u16x8 af[4], bfv[4];
#pragma unroll
            for (int m = 0; m < 4; ++m)
                af[m] = *(const u16x8*)&lA[(wr * 64 + m * 16 + (lane & 15)) * 64 + ks * 32 + (lane >> 4) * 8];
#pragma unroll
            for (int n = 0; n < 4; ++n)
                bfv[n] = *(const u16x8*)&lB[(wc * 64 + n * 16 + (lane & 15)) * 64 + ks * 32 + (lane >> 4) * 8];
#pragma unroll
            for (int m = 0; m < 4; ++m)
#pragma unroll
                for (int n = 0; n < 4; ++n)
                    acc[m][n] = mfma_bf16(af[m], bfv[n], acc[m][n]);
        }
        __syncthreads();
    }

#pragma unroll
    for (int m = 0; m < 4; ++m) {
#pragma unroll
        for (int n = 0; n < 4; ++n) {
#pragma unroll
            for (int j = 0; j < 4; ++j) {
                const int row = brow + wr * 64 + m * 16 + (lane >> 4) * 4 + j;
                const int col = bcol + wc * 64 + n * 16 + (lane & 15);
                const float val = acc[m][n][j];
                if (MODE == 0) {
                    const int part = col >> 11;
                    const int e = col & 2047;
                    const int hh = e >> 7, dd = e & 127;
                    const int bb = row >> 11, ll = row & 2047;
                    u16* dst = (part == 0) ? qp : (part == 1) ? kp : vp;
                    dst[((size_t)(bb * 16 + hh) * 2048 + ll) * 128 + dd] = f2bf(val);
                } else {
                    outf[(size_t)row * N + col] = val;
                }
            }
        }
    }
}

// ---------------- RoPE in-place on q,k (contiguous, (2*B*H*L) rows of 128) ----------------
__global__ __launch_bounds__(256) void rope_kernel(u16* __restrict__ qk,
                                                   const float* __restrict__ cosp,
                                                   const float* __restrict__ sinp) {
    const int gid  = blockIdx.x * 4 + (threadIdx.x >> 6);   // row index
    const int lane = threadIdx.x & 63;
    const int l    = gid & 2047;
    u16* row = qk + (size_t)gid * 128;
    const int d1 = lane, d2 = lane + 64;
    const float v1 = bf2f(row[d1]);
    const float v2 = bf2f(row[d2]);
    const float c1 = cosp[l * 128 + d1], s1 = sinp[l * 128 + d1];
    const float c2 = cosp[l * 128 + d2], s2 = sinp[l * 128 + d2];
    row[d1] = f2bf(v1 * c1 - v2 * s1);   // rot_half: -t[d+64] for d<64
    row[d2] = f2bf(v2 * c2 + v1 * s2);   //           +t[d-64] for d>=64
}

// ---------------- flash attention: causal + prefix key-padding mask ----------------
// Balanced pairing, SEQUENTIAL halves: block handles q-tile jB=31-jA then jA.
// grid(512), 4 waves, 16 q-rows/wave/half. XCD-clustered bh for L2 locality.
// Softmax reductions via DPP (no LDS pipe), defer-max (T13), exp2-domain.
// KV tiles clamped to len[b]; fully-dead q-tiles write zeros and skip.
__global__ __launch_bounds__(256, 2) void attn_kernel(
    const u16* __restrict__ Q, const u16* __restrict__ K, const u16* __restrict__ V,
    const int* __restrict__ lens, u16* __restrict__ O) {
    __shared__ u16 lK[64 * 136];    // K tile, padded row stride 136
    __shared__ u16 lVT[128 * 72];   // V transposed: [d][key], stride 72
    __shared__ u16 lP[4 * 16 * 72]; // per-wave P: [16 q][keys], stride 72

    const int tid = threadIdx.x, lane = tid & 63, wid = tid >> 6;
    const int g   = blockIdx.x;
    const int xcd = g & 7;
    const int s   = g >> 3;
    const int jA  = s >> 2;                 // 0..15
    const int bh  = (xcd << 2) | (s & 3);   // 0..31, clustered per XCD
    const int b   = bh >> 4;
    const int h   = bh & 15;
    const u16* qb = Q + (size_t)bh * 2048 * 128;
    const u16* kb = K + (size_t)bh * 2048 * 128;
    const u16* vb = V + (size_t)bh * 2048 * 128;
    const int lenb = lens[b];
    const int str = lane;            // staging row 0..63
    const int sdc = wid;             // staging d-chunk 0..3 (32 d each)
    const float scale2 = 0.12754245006257017f;   // (1/sqrt(128)) * log2(e)
    const float THR = 32.0f;                      // defer-max: P bounded by 2^(32*scale2)~2^4
    u16* lPw = lP + wid * (16 * 72);

    for (int half = 0; half < 2; ++half) {
        const int jq = half ? jA : (31 - jA);
        const int q0w = jq * 64 + wid * 16;

        if (jq * 64 >= lenb) {
            // whole q-tile masked off: output rows are zero
#pragma unroll
            for (int j = 0; j < 4; ++j) {
                const int qq = q0w + (lane >> 4) * 4 + j;
#pragma unroll
                for (int n = 0; n < 8; ++n) {
                    const int d = n * 16 + (lane & 15);
                    O[((size_t)b * 2048 + qq) * 2048 + h * 128 + d] = 0;
                }
            }
            continue;   // block-uniform (jq, lenb) -> no barrier divergence
        }

        const int nt_full = jq + 1;
        const int lt = (lenb + 63) >> 6;
        const int ktiles = nt_full < lt ? nt_full : lt;   // live KV tiles only

        // Q fragments in registers (already RoPE'd)
        u16x8 aq[4];
#pragma unroll
        for (int kc = 0; kc < 4; ++kc)
            aq[kc] = *(const u16x8*)(qb + (size_t)(q0w + (lane & 15)) * 128 + kc * 32 + (lane >> 4) * 8);

        float ms[4], ls[4];
        f32x4 ao[8];
#pragma unroll
        for (int j = 0; j < 4; ++j) { ms[j] = -1e30f; ls[j] = 0.f; }
#pragma unroll
        for (int n = 0; n < 8; ++n) ao[n] = (f32x4){0.f, 0.f, 0.f, 0.f};

        u16x8 pk[4], pv[4];
        // prologue: stage tile 0
        {
            const u16* ks = kb + (size_t)str * 128 + sdc * 32;
            const u16* vs = vb + (size_t)str * 128 + sdc * 32;
#pragma unroll
            for (int i = 0; i < 4; ++i) { pk[i] = *(const u16x8*)(ks + i * 8); pv[i] = *(const u16x8*)(vs + i * 8); }
        }
        __syncthreads();   // previous half's LDS reads complete before overwrite
#pragma unroll
        for (int i = 0; i < 4; ++i) {
            *(u16x8*)&lK[str * 136 + sdc * 32 + i * 8] = pk[i];
#pragma unroll
            for (int e = 0; e < 8; ++e)
                lVT[(sdc * 32 + i * 8 + e) * 72 + str] = pv[i][e];
        }
        __syncthreads();

        for (int t = 0; t < ktiles; ++t) {
            const bool pf = (t + 1 < ktiles);
            if (pf) {   // T14: issue next-tile loads before compute
                const u16* ks = kb + (size_t)((t + 1) * 64 + str) * 128 + sdc * 32;
                const u16* vs = vb + (size_t)((t + 1) * 64 + str) * 128 + sdc * 32;
#pragma unroll
                for (int i = 0; i < 4; ++i) { pk[i] = *(const u16x8*)(ks + i * 8); pv[i] = *(const u16x8*)(vs + i * 8); }
            }
            const int kv0 = t * 64;

            // ---- S = Q K^T ----
            f32x4 sv4[4];
#pragma unroll
            for (int n = 0; n < 4; ++n) sv4[n] = (f32x4){0.f, 0.f, 0.f, 0.f};
#pragma unroll
            for (int kc = 0; kc < 4; ++kc) {
                u16x8 bk[4];
#pragma unroll
                for (int n = 0; n < 4; ++n)
                    bk[n] = *(const u16x8*)&lK[(n * 16 + (lane & 15)) * 136 + kc * 32 + (lane >> 4) * 8];
#pragma unroll
                for (int n = 0; n < 4; ++n)
                    sv4[n] = mfma_bf16(aq[kc], bk[n], sv4[n]);
            }

            // ---- masked online softmax (fp32, exp2 domain, DPP reductions) ----
            const bool needmask = (t == jq) || (kv0 + 64 > lenb);
#pragma unroll
            for (int j = 0; j < 4; ++j) {
                const int row = (lane >> 4) * 4 + j;
                float sv[4];
                if (needmask) {
                    const int qq = q0w + row;
                    const int bound = (qq < lenb - 1) ? qq : (lenb - 1);
#pragma unroll
                    for (int n = 0; n < 4; ++n) {
                        const int kk = kv0 + n * 16 + (lane & 15);
                        sv[n] = (kk <= bound) ? sv4[n][j] : -1e30f;
                    }
                } else {
#pragma unroll
                    for (int n = 0; n < 4; ++n) sv[n] = sv4[n][j];
                }
                const float rm = red16_max(fmaxf(fmaxf(sv[0], sv[1]), fmaxf(sv[2], sv[3])));
                const float mo = ms[j];
                const bool grow = !__all(rm <= mo + THR);   // T13 defer-max
                if (grow) {
                    const float mn = fmaxf(mo, rm);
                    ms[j] = mn;
                    const float alpha = exp2f((mo - mn) * scale2);
                    ls[j] *= alpha;
#pragma unroll
                    for (int n = 0; n < 8; ++n) ao[n][j] *= alpha;
                }
                const float mk = ms[j] * scale2;
                float rs = 0.f;
#pragma unroll
                for (int n = 0; n < 4; ++n) {
                    const float p = exp2f(fmaf(sv[n], scale2, -mk));   // masked -> underflow 0
                    rs += p;
                    lPw[row * 72 + n * 16 + (lane & 15)] = f2bf(p);
                }
                ls[j] += red16_sum(rs);
            }

            // ---- O += P V ----
#pragma unroll
            for (int kc = 0; kc < 2; ++kc) {
                u16x8 ap = *(const u16x8*)&lPw[(lane & 15) * 72 + kc * 32 + (lane >> 4) * 8];
#pragma unroll
                for (int n = 0; n < 8; ++n) {
                    u16x8 bv = *(const u16x8*)&lVT[(n * 16 + (lane & 15)) * 72 + kc * 32 + (lane >> 4) * 8];
                    ao[n] = mfma_bf16(ap, bv, ao[n]);
                }
            }

            if (pf) {
                __syncthreads();   // all waves done reading lK/lVT
#pragma unroll
                for (int i = 0; i < 4; ++i) {
                    *(u16x8*)&lK[str * 136 + sdc * 32 + i * 8] = pk[i];
#pragma unroll
                    for (int e = 0; e < 8; ++e)
                        lVT[(sdc * 32 + i * 8 + e) * 72 + str] = pv[i][e];
                }
                __syncthreads();   // next tile staged
            }
        }

        // ---- epilogue: normalize, row-mask, write (B,L,D) ----
#pragma unroll
        for (int j = 0; j < 4; ++j) {
            const int qq = q0w + (lane >> 4) * 4 + j;
            const float inv = (qq < lenb) ? (1.f / ls[j]) : 0.f;
#pragma unroll
            for (int n = 0; n < 8; ++n) {
                const int d = n * 16 + (lane & 15);
                O[((size_t)b * 2048 + qq) * 2048 + h * 128 + d] = f2bf(ao[n][j] * inv);
            }
        }
    }
}

// ---------------- launch ----------------
extern "C" void kernel_launch(void* const* d_in, const int* in_sizes, int n_in,
                              void* d_out, int out_size, void* d_ws, size_t ws_size,
                              hipStream_t stream) {
    const float* x      = (const float*)d_in[0];
    const unsigned char* maskraw = (const unsigned char*)d_in[1];
    const float* cosp   = (const float*)d_in[2];
    const float* sinp   = (const float*)d_in[3];
    const float* w_qkv  = (const float*)d_in[4];
    const float* w_out  = (const float*)d_in[5];
    float* out = (float*)d_out;

    char* ws = (char*)d_ws;
    size_t off = 0;
    auto alloc = [&](size_t bytes) {
        char* p = ws + off;
        off += (bytes + 255) & ~(size_t)255;
        return p;
    };
    u16* xb    = (u16*)alloc((size_t)4096 * 2048 * 2);
    u16* wqkvb = (u16*)alloc((size_t)6144 * 2048 * 2);
    u16* woutb = (u16*)alloc((size_t)2048 * 2048 * 2);
    u16* qB    = (u16*)alloc((size_t)65536 * 128 * 2);  // (B,H,L,hd)
    u16* kB    = (u16*)alloc((size_t)65536 * 128 * 2);  // contiguous after qB (rope relies on it)
    u16* vB    = (u16*)alloc((size_t)65536 * 128 * 2);
    u16* attno = (u16*)alloc((size_t)4096 * 2048 * 2);
    int* lens  = (int*)alloc(256);

    cvt_kernel<<<dim3(4096 * 2048 / 4 / 256), dim3(256), 0, stream>>>(x, xb, 4096 * 2048 / 4);
    cvt_kernel<<<dim3(6144 * 2048 / 4 / 256), dim3(256), 0, stream>>>(w_qkv, wqkvb, 6144 * 2048 / 4);
    cvt_kernel<<<dim3(2048 * 2048 / 4 / 256), dim3(256), 0, stream>>>(w_out, woutb, 2048 * 2048 / 4);
    mask_prep<<<dim3(2), dim3(256), 0, stream>>>(maskraw, lens);

    gemm_bt<0><<<dim3(48, 32), dim3(256), 0, stream>>>(xb, wqkvb, 4096, 6144, 2048,
                                                       qB, kB, vB, nullptr);
    rope_kernel<<<dim3(131072 / 4), dim3(256), 0, stream>>>(qB, cosp, sinp);
    attn_kernel<<<dim3(512), dim3(256), 0, stream>>>(qB, kB, vB, lens, attno);
    gemm_bt<1><<<dim3(16, 32), dim3(256), 0, stream>>>(attno, woutb, 4096, 2048, 2048,
                                                       nullptr, nullptr, nullptr, out);
}

// Round 5
// 297.642 us; speedup vs baseline: 1.5445x; 1.0792x over previous
//
#include <hip/hip_runtime.h>

typedef unsigned short u16;
typedef u16 u16x8 __attribute__((ext_vector_type(8)));
typedef u16 u16x4 __attribute__((ext_vector_type(4)));
typedef __bf16 bf16x8_t __attribute__((ext_vector_type(8)));
typedef float f32x4 __attribute__((ext_vector_type(4)));

#define GLOBAL_AS __attribute__((address_space(1)))
#define LDS_AS __attribute__((address_space(3)))

__device__ __forceinline__ float bf2f(u16 v) {
    return __uint_as_float(((unsigned int)v) << 16);
}
__device__ __forceinline__ u16 f2bf(float f) {
    unsigned int u = __float_as_uint(f);
    u += 0x7fff + ((u >> 16) & 1);   // RTNE (no NaNs in this pipeline)
    return (u16)(u >> 16);
}

__device__ __forceinline__ f32x4 mfma_bf16(u16x8 a, u16x8 b, f32x4 c) {
    return __builtin_amdgcn_mfma_f32_16x16x32_bf16(
        __builtin_bit_cast(bf16x8_t, a), __builtin_bit_cast(bf16x8_t, b), c, 0, 0, 0);
}

// 16-lane (row) reductions via DPP — pure VALU, no LDS pipe.
__device__ __forceinline__ float red16_max(float x) {
    int t;
    t = __builtin_amdgcn_update_dpp(0, __builtin_bit_cast(int, x), 0xB1, 0xF, 0xF, true);
    x = fmaxf(x, __builtin_bit_cast(float, t));
    t = __builtin_amdgcn_update_dpp(0, __builtin_bit_cast(int, x), 0x4E, 0xF, 0xF, true);
    x = fmaxf(x, __builtin_bit_cast(float, t));
    t = __builtin_amdgcn_update_dpp(0, __builtin_bit_cast(int, x), 0x124, 0xF, 0xF, true);
    x = fmaxf(x, __builtin_bit_cast(float, t));
    t = __builtin_amdgcn_update_dpp(0, __builtin_bit_cast(int, x), 0x128, 0xF, 0xF, true);
    x = fmaxf(x, __builtin_bit_cast(float, t));
    return x;
}
__device__ __forceinline__ float red16_sum(float x) {
    int t;
    t = __builtin_amdgcn_update_dpp(0, __builtin_bit_cast(int, x), 0xB1, 0xF, 0xF, true);
    x += __builtin_bit_cast(float, t);
    t = __builtin_amdgcn_update_dpp(0, __builtin_bit_cast(int, x), 0x4E, 0xF, 0xF, true);
    x += __builtin_bit_cast(float, t);
    t = __builtin_amdgcn_update_dpp(0, __builtin_bit_cast(int, x), 0x124, 0xF, 0xF, true);
    x += __builtin_bit_cast(float, t);
    t = __builtin_amdgcn_update_dpp(0, __builtin_bit_cast(int, x), 0x128, 0xF, 0xF, true);
    x += __builtin_bit_cast(float, t);
    return x;
}

// ---------------- fp32 -> bf16 convert ----------------
__global__ __launch_bounds__(256) void cvt_kernel(const float* __restrict__ in,
                                                  u16* __restrict__ out, int n4) {
    int i = blockIdx.x * 256 + threadIdx.x;
    if (i >= n4) return;
    float4 f = ((const float4*)in)[i];
    u16x4 o = { f2bf(f.x), f2bf(f.y), f2bf(f.z), f2bf(f.w) };
    ((u16x4*)out)[i] = o;
}

// ---------------- keep-mask -> per-batch length (mask is a prefix mask) ----------------
__global__ __launch_bounds__(256) void mask_prep(const unsigned char* __restrict__ raw,
                                                 int* __restrict__ lens) {
    const int b = blockIdx.x;
    const int tid = threadIdx.x, lane = tid & 63, wid = tid >> 6;
    const unsigned char b0 = raw[0];
    int cnt = 0;
    for (int i = tid; i < 2048; i += 256) {
        const size_t idx = (size_t)b * 2048 + i;
        bool v;
        if (b0 == 0) {                       // fp32 (1.0f -> bytes 00 00 80 3f)
            v = ((const float*)raw)[idx] != 0.0f;
        } else if (b0 == 0x80) {             // bf16 (1.0 -> 0x3F80)
            v = ((const u16*)raw)[idx] != 0;
        } else {                             // integer of width 1/2/4/8
            const int stride = raw[1] ? 1 : (raw[2] ? 2 : (raw[4] ? 4 : 8));
            v = raw[idx * stride] != 0;
        }
        cnt += v ? 1 : 0;
    }
    cnt += __shfl_xor(cnt, 1);
    cnt += __shfl_xor(cnt, 2);
    cnt += __shfl_xor(cnt, 4);
    cnt += __shfl_xor(cnt, 8);
    cnt += __shfl_xor(cnt, 16);
    cnt += __shfl_xor(cnt, 32);
    __shared__ int wsum[4];
    if (lane == 0) wsum[wid] = cnt;
    __syncthreads();
    if (tid == 0) lens[b] = wsum[0] + wsum[1] + wsum[2] + wsum[3];
}

// ---------------- 256x128 bf16 GEMM, C = A(MxK) * B(NxK)^T ----------------
// T3/T4 pipeline: triple-buffered LDS, prefetch depth 2, counted vmcnt(6),
// raw s_barrier (1 per K-tile). T2: read-side XOR swizzle with pre-swizzled
// global source (LDS dest stays linear for global_load_lds). T1: XCD swizzle.
// MODE 0: scatter to q/k/v (B,H,L,hd) bf16.  MODE 1: fp32 out[M][N].
template <int MODE>
__global__ __launch_bounds__(512, 2) void gemm_bt(
    const u16* __restrict__ A, const u16* __restrict__ B,
    int M, int N, int K, int nbx,
    u16* __restrict__ qp, u16* __restrict__ kp, u16* __restrict__ vp,
    float* __restrict__ outf) {
    __shared__ u16 lds[3 * 24576];   // 3 bufs x (A 256x64 | B 128x64) = 144 KB
    const int tid  = threadIdx.x;
    const int lane = tid & 63;
    const int wid  = tid >> 6;
    const int wm   = wid >> 1;       // 0..3 (M quarters of 64 rows)
    const int wn   = wid & 1;        // 0..1 (N halves of 64 cols)

    // XCD-aware swizzle (grid % 8 == 0 for both call sites)
    const int cpx = (int)gridDim.x >> 3;
    const int bid = blockIdx.x;
    const int swz = (bid & 7) * cpx + (bid >> 3);
    const int bx = swz % nbx, by = swz / nbx;
    const int brow = by * 256;
    const int bcol = bx * 128;

    f32x4 acc[4][4];
#pragma unroll
    for (int m = 0; m < 4; ++m)
#pragma unroll
        for (int n = 0; n < 4; ++n)
            acc[m][n] = (f32x4){0.f, 0.f, 0.f, 0.f};

    // staging: thread tid writes LDS bytes [i*8192 + tid*16); row = i*64+(tid>>3),
    // granule gL = tid&7. Source granule = gL ^ (row&7) = (tid&7)^((tid>>3)&7).
    const int scol  = (((tid & 7) ^ ((tid >> 3) & 7)) << 3);   // bf16 col within K-tile
    const int arow0 = tid >> 3;                                 // 0..63
    const u16* aBase = A + (size_t)(brow + arow0) * K + scol;
    const u16* bBase = B + (size_t)(bcol + arow0) * K + scol;

    auto stage = [&](int kt, int bb) {
        char* base = (char*)lds + bb * 49152;
        const u16* as = aBase + kt * 64;
        const u16* bs = bBase + kt * 64;
#pragma unroll
        for (int i = 0; i < 4; ++i)
            __builtin_amdgcn_global_load_lds((const GLOBAL_AS void*)(as + (size_t)(i * 64) * K),
                (LDS_AS void*)(base + i * 8192 + wid * 1024), 16, 0, 0);
#pragma unroll
        for (int i = 0; i < 2; ++i)
            __builtin_amdgcn_global_load_lds((const GLOBAL_AS void*)(bs + (size_t)(i * 64) * K),
                (LDS_AS void*)(base + 32768 + i * 8192 + wid * 1024), 16, 0, 0);
    };

    const int nkt = K >> 6;
    stage(0, 0);
    stage(1, 1);

    int bufc = 0;
    for (int kt = 0; kt < nkt; ++kt) {
        // wait ONLY for tile kt's 6 loads; tile kt+1's 6 stay in flight
        if (kt + 1 < nkt) asm volatile("s_waitcnt vmcnt(6)" ::: "memory");
        else              asm volatile("s_waitcnt vmcnt(0)" ::: "memory");
        __builtin_amdgcn_s_barrier();
        __builtin_amdgcn_sched_barrier(0);

        if (kt + 2 < nkt) {
            int nb = bufc + 2; if (nb >= 3) nb -= 3;
            stage(kt + 2, nb);
        }

        const u16* lA = lds + bufc * 24576;
        const u16* lB = lA + 16384;
        u16x8 af[4][2], bfr[4][2];
#pragma unroll
        for (int m = 0; m < 4; ++m)
#pragma unroll
            for (int ks = 0; ks < 2; ++ks) {
                const int row = wm * 64 + m * 16 + (lane & 15);
                const int g = ((ks << 2) + (lane >> 4)) ^ (lane & 7);
                af[m][ks] = *(const u16x8*)&lA[row * 64 + (g << 3)];
            }
#pragma unroll
        for (int n = 0; n < 4; ++n)
#pragma unroll
            for (int ks = 0; ks < 2; ++ks) {
                const int row = wn * 64 + n * 16 + (lane & 15);
                const int g = ((ks << 2) + (lane >> 4)) ^ (lane & 7);
                bfr[n][ks] = *(const u16x8*)&lB[row * 64 + (g << 3)];
            }

        __builtin_amdgcn_s_setprio(1);
#pragma unroll
        for (int ks = 0; ks < 2; ++ks)
#pragma unroll
            for (int m = 0; m < 4; ++m)
#pragma unroll
                for (int n = 0; n < 4; ++n)
                    acc[m][n] = mfma_bf16(af[m][ks], bfr[n][ks], acc[m][n]);
        __builtin_amdgcn_s_setprio(0);

        ++bufc; if (bufc == 3) bufc = 0;
    }

#pragma unroll
    for (int m = 0; m < 4; ++m) {
#pragma unroll
        for (int n = 0; n < 4; ++n) {
#pragma unroll
            for (int j = 0; j < 4; ++j) {
                const int row = brow + wm * 64 + m * 16 + (lane >> 4) * 4 + j;
                const int col = bcol + wn * 64 + n * 16 + (lane & 15);
                const float val = acc[m][n][j];
                if (MODE == 0) {
                    const int part = col >> 11;
                    const int e = col & 2047;
                    const int hh = e >> 7, dd = e & 127;
                    const int bb = row >> 11, ll = row & 2047;
                    u16* dst = (part == 0) ? qp : (part == 1) ? kp : vp;
                    dst[((size_t)(bb * 16 + hh) * 2048 + ll) * 128 + dd] = f2bf(val);
                } else {
                    outf[(size_t)row * N + col] = val;
                }
            }
        }
    }
}

// ---------------- RoPE in-place on q,k (contiguous, (2*B*H*L) rows of 128) ----------------
__global__ __launch_bounds__(256) void rope_kernel(u16* __restrict__ qk,
                                                   const float* __restrict__ cosp,
                                                   const float* __restrict__ sinp) {
    const int gid  = blockIdx.x * 4 + (threadIdx.x >> 6);   // row index
    const int lane = threadIdx.x & 63;
    const int l    = gid & 2047;
    u16* row = qk + (size_t)gid * 128;
    const int d1 = lane, d2 = lane + 64;
    const float v1 = bf2f(row[d1]);
    const float v2 = bf2f(row[d2]);
    const float c1 = cosp[l * 128 + d1], s1 = sinp[l * 128 + d1];
    const float c2 = cosp[l * 128 + d2], s2 = sinp[l * 128 + d2];
    row[d1] = f2bf(v1 * c1 - v2 * s1);   // rot_half: -t[d+64] for d<64
    row[d2] = f2bf(v2 * c2 + v1 * s2);   //           +t[d-64] for d>=64
}

// ---------------- flash attention: causal + prefix key-padding mask ----------------
__global__ __launch_bounds__(256, 2) void attn_kernel(
    const u16* __restrict__ Q, const u16* __restrict__ K, const u16* __restrict__ V,
    const int* __restrict__ lens, u16* __restrict__ O) {
    __shared__ u16 lK[64 * 136];    // K tile, padded row stride 136
    __shared__ u16 lVT[128 * 72];   // V transposed: [d][key], stride 72
    __shared__ u16 lP[4 * 16 * 72]; // per-wave P: [16 q][keys], stride 72

    const int tid = threadIdx.x, lane = tid & 63, wid = tid >> 6;
    const int g   = blockIdx.x;
    const int xcd = g & 7;
    const int s   = g >> 3;
    const int jA  = s >> 2;                 // 0..15
    const int bh  = (xcd << 2) | (s & 3);   // 0..31, clustered per XCD
    const int b   = bh >> 4;
    const int h   = bh & 15;
    const u16* qb = Q + (size_t)bh * 2048 * 128;
    const u16* kb = K + (size_t)bh * 2048 * 128;
    const u16* vb = V + (size_t)bh * 2048 * 128;
    const int lenb = lens[b];
    const int str = lane;            // staging row 0..63
    const int sdc = wid;             // staging d-chunk 0..3 (32 d each)
    const float scale2 = 0.12754245006257017f;   // (1/sqrt(128)) * log2(e)
    const float THR = 32.0f;                      // defer-max
    u16* lPw = lP + wid * (16 * 72);

    for (int half = 0; half < 2; ++half) {
        const int jq = half ? jA : (31 - jA);
        const int q0w = jq * 64 + wid * 16;

        if (jq * 64 >= lenb) {
#pragma unroll
            for (int j = 0; j < 4; ++j) {
                const int qq = q0w + (lane >> 4) * 4 + j;
#pragma unroll
                for (int n = 0; n < 8; ++n) {
                    const int d = n * 16 + (lane & 15);
                    O[((size_t)b * 2048 + qq) * 2048 + h * 128 + d] = 0;
                }
            }
            continue;   // block-uniform (jq, lenb) -> no barrier divergence
        }

        const int nt_full = jq + 1;
        const int lt = (lenb + 63) >> 6;
        const int ktiles = nt_full < lt ? nt_full : lt;   // live KV tiles only

        u16x8 aq[4];
#pragma unroll
        for (int kc = 0; kc < 4; ++kc)
            aq[kc] = *(const u16x8*)(qb + (size_t)(q0w + (lane & 15)) * 128 + kc * 32 + (lane >> 4) * 8);

        float ms[4], ls[4];
        f32x4 ao[8];
#pragma unroll
        for (int j = 0; j < 4; ++j) { ms[j] = -1e30f; ls[j] = 0.f; }
#pragma unroll
        for (int n = 0; n < 8; ++n) ao[n] = (f32x4){0.f, 0.f, 0.f, 0.f};

        u16x8 pk[4], pv[4];
        {
            const u16* ks = kb + (size_t)str * 128 + sdc * 32;
            const u16* vs = vb + (size_t)str * 128 + sdc * 32;
#pragma unroll
            for (int i = 0; i < 4; ++i) { pk[i] = *(const u16x8*)(ks + i * 8); pv[i] = *(const u16x8*)(vs + i * 8); }
        }
        __syncthreads();   // previous half's LDS reads complete before overwrite
#pragma unroll
        for (int i = 0; i < 4; ++i) {
            *(u16x8*)&lK[str * 136 + sdc * 32 + i * 8] = pk[i];
#pragma unroll
            for (int e = 0; e < 8; ++e)
                lVT[(sdc * 32 + i * 8 + e) * 72 + str] = pv[i][e];
        }
        __syncthreads();

        for (int t = 0; t < ktiles; ++t) {
            const bool pf = (t + 1 < ktiles);
            if (pf) {   // T14: issue next-tile loads before compute
                const u16* ks = kb + (size_t)((t + 1) * 64 + str) * 128 + sdc * 32;
                const u16* vs = vb + (size_t)((t + 1) * 64 + str) * 128 + sdc * 32;
#pragma unroll
                for (int i = 0; i < 4; ++i) { pk[i] = *(const u16x8*)(ks + i * 8); pv[i] = *(const u16x8*)(vs + i * 8); }
            }
            const int kv0 = t * 64;

            f32x4 sv4[4];
#pragma unroll
            for (int n = 0; n < 4; ++n) sv4[n] = (f32x4){0.f, 0.f, 0.f, 0.f};
#pragma unroll
            for (int kc = 0; kc < 4; ++kc) {
                u16x8 bk[4];
#pragma unroll
                for (int n = 0; n < 4; ++n)
                    bk[n] = *(const u16x8*)&lK[(n * 16 + (lane & 15)) * 136 + kc * 32 + (lane >> 4) * 8];
#pragma unroll
                for (int n = 0; n < 4; ++n)
                    sv4[n] = mfma_bf16(aq[kc], bk[n], sv4[n]);
            }

            const bool needmask = (t == jq) || (kv0 + 64 > lenb);
#pragma unroll
            for (int j = 0; j < 4; ++j) {
                const int row = (lane >> 4) * 4 + j;
                float sv[4];
                if (needmask) {
                    const int qq = q0w + row;
                    const int bound = (qq < lenb - 1) ? qq : (lenb - 1);
#pragma unroll
                    for (int n = 0; n < 4; ++n) {
                        const int kk = kv0 + n * 16 + (lane & 15);
                        sv[n] = (kk <= bound) ? sv4[n][j] : -1e30f;
                    }
                } else {
#pragma unroll
                    for (int n = 0; n < 4; ++n) sv[n] = sv4[n][j];
                }
                const float rm = red16_max(fmaxf(fmaxf(sv[0], sv[1]), fmaxf(sv[2], sv[3])));
                const float mo = ms[j];
                const bool grow = !__all(rm <= mo + THR);   // T13 defer-max
                if (grow) {
                    const float mn = fmaxf(mo, rm);
                    ms[j] = mn;
                    const float alpha = exp2f((mo - mn) * scale2);
                    ls[j] *= alpha;
#pragma unroll
                    for (int n = 0; n < 8; ++n) ao[n][j] *= alpha;
                }
                const float mk = ms[j] * scale2;
                float rs = 0.f;
#pragma unroll
                for (int n = 0; n < 4; ++n) {
                    const float p = exp2f(fmaf(sv[n], scale2, -mk));   // masked -> underflow 0
                    rs += p;
                    lPw[row * 72 + n * 16 + (lane & 15)] = f2bf(p);
                }
                ls[j] += red16_sum(rs);
            }

#pragma unroll
            for (int kc = 0; kc < 2; ++kc) {
                u16x8 ap = *(const u16x8*)&lPw[(lane & 15) * 72 + kc * 32 + (lane >> 4) * 8];
#pragma unroll
                for (int n = 0; n < 8; ++n) {
                    u16x8 bv = *(const u16x8*)&lVT[(n * 16 + (lane & 15)) * 72 + kc * 32 + (lane >> 4) * 8];
                    ao[n] = mfma_bf16(ap, bv, ao[n]);
                }
            }

            if (pf) {
                __syncthreads();
#pragma unroll
                for (int i = 0; i < 4; ++i) {
                    *(u16x8*)&lK[str * 136 + sdc * 32 + i * 8] = pk[i];
#pragma unroll
                    for (int e = 0; e < 8; ++e)
                        lVT[(sdc * 32 + i * 8 + e) * 72 + str] = pv[i][e];
                }
                __syncthreads();
            }
        }

#pragma unroll
        for (int j = 0; j < 4; ++j) {
            const int qq = q0w + (lane >> 4) * 4 + j;
            const float inv = (qq < lenb) ? (1.f / ls[j]) : 0.f;
#pragma unroll
            for (int n = 0; n < 8; ++n) {
                const int d = n * 16 + (lane & 15);
                O[((size_t)b * 2048 + qq) * 2048 + h * 128 + d] = f2bf(ao[n][j] * inv);
            }
        }
    }
}

// ---------------- launch ----------------
extern "C" void kernel_launch(void* const* d_in, const int* in_sizes, int n_in,
                              void* d_out, int out_size, void* d_ws, size_t ws_size,
                              hipStream_t stream) {
    const float* x      = (const float*)d_in[0];
    const unsigned char* maskraw = (const unsigned char*)d_in[1];
    const float* cosp   = (const float*)d_in[2];
    const float* sinp   = (const float*)d_in[3];
    const float* w_qkv  = (const float*)d_in[4];
    const float* w_out  = (const float*)d_in[5];
    float* out = (float*)d_out;

    char* ws = (char*)d_ws;
    size_t off = 0;
    auto alloc = [&](size_t bytes) {
        char* p = ws + off;
        off += (bytes + 255) & ~(size_t)255;
        return p;
    };
    u16* xb    = (u16*)alloc((size_t)4096 * 2048 * 2);
    u16* wqkvb = (u16*)alloc((size_t)6144 * 2048 * 2);
    u16* woutb = (u16*)alloc((size_t)2048 * 2048 * 2);
    u16* qB    = (u16*)alloc((size_t)65536 * 128 * 2);  // (B,H,L,hd)
    u16* kB    = (u16*)alloc((size_t)65536 * 128 * 2);  // contiguous after qB (rope relies on it)
    u16* vB    = (u16*)alloc((size_t)65536 * 128 * 2);
    u16* attno = (u16*)alloc((size_t)4096 * 2048 * 2);
    int* lens  = (int*)alloc(256);

    cvt_kernel<<<dim3(4096 * 2048 / 4 / 256), dim3(256), 0, stream>>>(x, xb, 4096 * 2048 / 4);
    cvt_kernel<<<dim3(6144 * 2048 / 4 / 256), dim3(256), 0, stream>>>(w_qkv, wqkvb, 6144 * 2048 / 4);
    cvt_kernel<<<dim3(2048 * 2048 / 4 / 256), dim3(256), 0, stream>>>(w_out, woutb, 2048 * 2048 / 4);
    mask_prep<<<dim3(2), dim3(256), 0, stream>>>(maskraw, lens);

    gemm_bt<0><<<dim3(768), dim3(512), 0, stream>>>(xb, wqkvb, 4096, 6144, 2048, 48,
                                                    qB, kB, vB, nullptr);
    rope_kernel<<<dim3(131072 / 4), dim3(256), 0, stream>>>(qB, cosp, sinp);
    attn_kernel<<<dim3(512), dim3(256), 0, stream>>>(qB, kB, vB, lens, attno);
    gemm_bt<1><<<dim3(256), dim3(512), 0, stream>>>(attno, woutb, 4096, 2048, 2048, 16,
                                                    nullptr, nullptr, nullptr, out);
}